// Round 1
// baseline (913.063 us; speedup 1.0000x reference)
//
#include <hip/hip_runtime.h>
#include <cstdint>
#include <cstddef>

#define N_TOT   147456      // 9*128*128
#define K_PRE   6000
#define K_POST  300
#define CAP     32768       // candidate cap (expected ~9.2K)
#define MW      188         // 6016 bits per mask row -> 188 u32 words
#define ROWS_PAD 6016       // padded mask rows (garbage rows masked by surv bits)

__constant__ float c_sizes[9] = {4.f,8.f,12.f,16.f,24.f,32.f,48.f,64.f,96.f};

// Bit-exact replication of reference box math (anchor + delta, clip). No
// fusable mul+add patterns -> no FMA-contraction divergence vs numpy ref.
__device__ __forceinline__ void compute_box(int idx, const float* __restrict__ deltas,
                                            float& px1, float& py1, float& pw, float& ph) {
    int a   = idx >> 14;          // idx / 16384
    int rem = idx & 16383;        // h*128 + w
    int h   = rem >> 7;
    int w   = rem & 127;
    float s    = c_sizes[a];
    float half = s * 0.5f;
    // deltas reshape (1,36,128,128)->(1,9,128,128,4): flat = a*65536 + rem*4 + d
    const float4 d = *(const float4*)(deltas + (size_t)a * 65536 + (size_t)rem * 4);
    float b0 = (((float)h + 0.5f) - half) + d.x;   // x0 + dx
    float b1 = (((float)w + 0.5f) - half) + d.y;   // y0 + dy
    float b2 = s + d.z;
    float b3 = s + d.w;
    b0 = fmaxf(b0, 0.0f); b1 = fmaxf(b1, 0.0f);
    b2 = fmaxf(b2, 0.0f); b3 = fmaxf(b3, 0.0f);
    float x1 = b0, y1 = b1;
    float x2 = b0 + b2, y2 = b1 + b3;
    x1 = fminf(x1, 128.0f); y1 = fminf(y1, 128.0f);
    x2 = fminf(x2, 128.0f); y2 = fminf(y2, 128.0f);
    px1 = x1; py1 = y1; pw = x2 - x1; ph = y2 - y1;
}

__global__ void k_init(float* out, uint32_t* hist, uint32_t* meta) {
    int g = blockIdx.x * 256 + threadIdx.x;
    if (g < K_POST * 4) out[g] = 0.0f;
    if (g < 4096) hist[g] = 0u;
    if (g < 16) meta[g] = 0u;
}

// keys: monotonic u32 score key (0 if min-size filtered) + 4096-bin histogram of top-12 bits
__global__ void k_keys_hist(const float* __restrict__ scores, const float* __restrict__ deltas,
                            uint32_t* __restrict__ keys, uint32_t* __restrict__ hist) {
    __shared__ uint32_t lh[4096];
    for (int i = threadIdx.x; i < 4096; i += 256) lh[i] = 0u;
    __syncthreads();
    int idx = blockIdx.x * 256 + threadIdx.x;
    float px1, py1, pw, ph;
    compute_box(idx, deltas, px1, py1, pw, ph);
    bool keep = (pw >= 3.0f) && (ph >= 3.0f);
    float sc = scores[idx];                     // scores flat order == box flat order (A,H,W)
    uint32_t key = keep ? __float_as_uint(sc) : 0u;   // sc >= 0 -> bits monotonic
    keys[idx] = key;
    atomicAdd(&lh[key >> 20], 1u);
    __syncthreads();
    for (int i = threadIdx.x; i < 4096; i += 256) {
        uint32_t v = lh[i];
        if (v) atomicAdd(&hist[i], v);
    }
}

// find smallest top-bin set with cumulative count >= 6000; meta[0] = threshold bin
__global__ void k_findbin(const uint32_t* __restrict__ hist, uint32_t* meta) {
    __shared__ uint32_t lh[4096];
    __shared__ uint32_t seg[256];
    for (int i = threadIdx.x; i < 4096; i += 256) lh[i] = hist[i];
    __syncthreads();
    uint32_t s = 0;
    for (int q = 0; q < 16; q++) s += lh[threadIdx.x * 16 + q];
    seg[threadIdx.x] = s;
    __syncthreads();
    if (threadIdx.x == 0) {
        uint32_t cum = 0;
        for (int t = 255; t >= 0; t--) {
            if (cum + seg[t] >= K_PRE) {
                uint32_t c2 = cum;
                for (int q = 15; q >= 0; q--) {
                    int bin = t * 16 + q;
                    c2 += lh[bin];
                    if (c2 >= K_PRE) { meta[0] = (uint32_t)bin; return; }
                }
            }
            cum += seg[t];
        }
        meta[0] = 0u;
    }
}

// compact candidates (key in threshold bin or above) as u64 (score_bits<<32 | ~idx)
__global__ void k_compact(const uint32_t* __restrict__ keys, const uint32_t* __restrict__ meta,
                          uint64_t* __restrict__ cand, uint32_t* counter) {
    int idx = blockIdx.x * 256 + threadIdx.x;
    uint32_t bstar = meta[0];
    uint32_t key = keys[idx];
    if ((key >> 20) >= bstar) {
        uint32_t pos = atomicAdd(counter, 1u);
        if (pos < CAP) cand[pos] = ((uint64_t)key << 32) | (uint32_t)(~(uint32_t)idx);
    }
}

// exact rank-by-count over candidates: reproduces top_k (score desc, idx asc) ordering
__global__ void k_rank_score(const uint64_t* __restrict__ cand, const uint32_t* __restrict__ meta,
                             uint32_t* __restrict__ top) {
    __shared__ uint64_t lk[2048];
    uint32_t C = meta[1];
    if (C > CAP) C = CAP;
    int g = blockIdx.x * 256 + threadIdx.x;
    uint64_t my = (g < (int)C) ? cand[g] : 0ull;
    uint32_t cnt = 0;
    for (uint32_t base = 0; base < C; base += 2048) {
        uint32_t n = min(2048u, C - base);
        for (uint32_t i = threadIdx.x; i < 2048; i += 256)
            lk[i] = (base + i < C) ? cand[base + i] : 0ull;
        __syncthreads();
        for (uint32_t j = 0; j < n; j++) cnt += (lk[j] > my) ? 1u : 0u;
        __syncthreads();
    }
    if (g < (int)C && cnt < K_PRE) top[cnt] = ~((uint32_t)my);
}

// gather top-6000 props in score order + build y2 sort keys (y2 desc, rank asc)
__global__ void k_props(const uint32_t* __restrict__ top, const float* __restrict__ deltas,
                        float4* __restrict__ P, uint64_t* __restrict__ ykey) {
    int r = blockIdx.x * 256 + threadIdx.x;
    if (r >= K_PRE) return;
    int idx = (int)top[r];
    float px1, py1, pw, ph;
    compute_box(idx, deltas, px1, py1, pw, ph);
    P[r] = make_float4(px1, py1, pw, ph);
    float y2 = py1 + ph;                        // y2 >= 3 -> bits monotonic
    ykey[r] = ((uint64_t)__float_as_uint(y2) << 32) | (uint32_t)(~(uint32_t)r);
}

// stable sort by y2 desc via rank-by-count; scatter ordered props / corners / area
__global__ void k_rank_y2(const uint64_t* __restrict__ ykey, const float4* __restrict__ P,
                          float4* __restrict__ OP, float4* __restrict__ Q, float* __restrict__ A) {
    __shared__ uint64_t lk[2048];
    int r = blockIdx.x * 256 + threadIdx.x;
    uint64_t my = (r < K_PRE) ? ykey[r] : 0ull;
    uint32_t cnt = 0;
    for (int base = 0; base < K_PRE; base += 2048) {
        int n = min(2048, K_PRE - base);
        for (int i = threadIdx.x; i < 2048; i += 256)
            lk[i] = (base + i < K_PRE) ? ykey[base + i] : 0ull;
        __syncthreads();
        for (int j = 0; j < n; j++) cnt += (lk[j] > my) ? 1u : 0u;
        __syncthreads();
    }
    if (r < K_PRE) {
        float4 p = P[r];
        OP[cnt] = p;
        float x1 = p.x, y1 = p.y;
        float x2 = x1 + p.z, y2 = y1 + p.w;                 // same op order as reference
        float area = fmaxf((x2 - x1) * (y2 - y1), 1e-6f);
        Q[cnt] = make_float4(x1, y1, x2, y2);
        A[cnt] = area;
    }
}

// suppression bitmask: bit j of row i = (ov[i][j] >= 0.7 && j != i). IEEE div kept.
__global__ void k_mask(const float4* __restrict__ Q, const float* __restrict__ A,
                       uint32_t* __restrict__ mask) {
    int g = blockIdx.x * 256 + threadIdx.x;
    if (g >= K_PRE * MW) return;
    int i  = g / MW;
    int wj = g - i * MW;
    float4 qi = Q[i];
    uint32_t bits = 0u;
    int jbase = wj * 32;
    #pragma unroll 4
    for (int b = 0; b < 32; b++) {
        int j = jbase + b;
        if (j < K_PRE && j != i) {
            float4 qj = Q[j];
            float iw = fminf(qi.z, qj.z) - fmaxf(qi.x, qj.x) + 1.0f;
            iw = fmaxf(iw, 0.0f);
            float ih = fminf(qi.w, qj.w) - fmaxf(qi.y, qj.y) + 1.0f;
            ih = fmaxf(ih, 0.0f);
            float ov = (iw * ih) / A[j];
            if (ov >= 0.7f) bits |= (1u << b);
        }
    }
    mask[(size_t)i * MW + wj] = bits;
}

// single-block chunked sequential NMS scan + output of first 300 valid rows.
// Key fact: backward suppression (j < i) never changes future decisions, only
// final validity -> chunk of 64 rows decided from intra-chunk 64x64 bits +
// incoming rem; then surviving rows' full mask rows bulk-ORed into rem.
__global__ void __launch_bounds__(256) k_scan(const uint32_t* __restrict__ mask,
                                              const float4* __restrict__ OP,
                                              float* __restrict__ out) {
    __shared__ uint32_t rem[MW];
    __shared__ uint32_t survLDS[2];
    __shared__ uint32_t cnts[MW];
    for (int i = threadIdx.x; i < MW; i += 256) rem[i] = 0u;
    __syncthreads();

    for (int c = 0; c < 94; c++) {
        int base = c * 64;
        int rows = min(64, K_PRE - base);
        if (threadIdx.x < 64) {
            int k = threadIdx.x;
            const uint32_t* rp = mask + (size_t)(base + k) * MW + 2 * c;
            uint32_t rlo = rp[0], rhi = rp[1];                 // row k, intra-chunk columns
            uint64_t myrow = ((uint64_t)rhi << 32) | rlo;
            uint64_t v = ((uint64_t)(uint32_t)(~rem[2 * c + 1]) << 32) | (uint32_t)(~rem[2 * c]);
            uint64_t surv = 0ull;
            for (int kk = 0; kk < 64; kk++) {
                uint64_t row = (uint64_t)__shfl((long long)myrow, kk, 64);
                bool alive = (((v >> kk) & 1ull) != 0ull) && (kk < rows);
                if (alive) { surv |= (1ull << kk); v &= ~row; }
            }
            if (k == 0) { survLDS[0] = (uint32_t)surv; survLDS[1] = (uint32_t)(surv >> 32); }
        }
        __syncthreads();
        uint64_t surv = ((uint64_t)survLDS[1] << 32) | survLDS[0];
        if (threadIdx.x < MW) {
            uint32_t acc = rem[threadIdx.x];
            const uint32_t* rp = mask + (size_t)base * MW + threadIdx.x;
            #pragma unroll
            for (int kb = 0; kb < 64; kb += 16) {
                uint32_t sv = (uint32_t)((surv >> kb) & 0xFFFFull);
                if (sv) {                                      // wave-uniform skip
                    uint32_t t[16];
                    #pragma unroll
                    for (int q = 0; q < 16; q++) t[q] = rp[(size_t)(kb + q) * MW];
                    #pragma unroll
                    for (int q = 0; q < 16; q++) if ((sv >> q) & 1u) acc |= t[q];
                }
            }
            rem[threadIdx.x] = acc;
        }
        __syncthreads();
    }

    // output: first 300 valid (ascending position), rest stay zero (k_init)
    if (threadIdx.x < MW) {
        uint32_t vw = ~rem[threadIdx.x];
        if (threadIdx.x == MW - 1) vw &= 0xFFFFu;              // bits 5984..5999 only
        cnts[threadIdx.x] = (uint32_t)__popc(vw);
    }
    __syncthreads();
    if (threadIdx.x == 0) {
        uint32_t run = 0;
        for (int w = 0; w < MW; w++) { uint32_t t = cnts[w]; cnts[w] = run; run += t; }
    }
    __syncthreads();
    if (threadIdx.x < MW) {
        uint32_t vw = ~rem[threadIdx.x];
        if (threadIdx.x == MW - 1) vw &= 0xFFFFu;
        uint32_t r = cnts[threadIdx.x];
        int wbase = threadIdx.x * 32;
        while (vw && r < K_POST) {
            int b = __ffs(vw) - 1;
            vw &= vw - 1u;
            float4 p = OP[wbase + b];
            *(float4*)(out + (size_t)r * 4) = p;
            r++;
        }
    }
}

extern "C" void kernel_launch(void* const* d_in, const int* in_sizes, int n_in,
                              void* d_out, int out_size, void* d_ws, size_t ws_size,
                              hipStream_t stream) {
    (void)in_sizes; (void)n_in; (void)out_size; (void)ws_size;
    const float* scores = (const float*)d_in[0];
    const float* deltas = (const float*)d_in[1];
    float* out = (float*)d_out;

    char* ws = (char*)d_ws;
    size_t off = 0;
    auto alloc = [&](size_t bytes) -> void* {
        void* p = ws + off;
        off += (bytes + 255) & ~(size_t)255;
        return p;
    };
    uint32_t* keys = (uint32_t*)alloc((size_t)N_TOT * 4);
    uint32_t* hist = (uint32_t*)alloc(4096 * 4);
    uint32_t* meta = (uint32_t*)alloc(64);
    uint64_t* cand = (uint64_t*)alloc((size_t)CAP * 8);
    uint32_t* top  = (uint32_t*)alloc((size_t)K_PRE * 4);
    float4*   P    = (float4*)alloc((size_t)K_PRE * 16);
    uint64_t* yk   = (uint64_t*)alloc((size_t)K_PRE * 8);
    float4*   OP   = (float4*)alloc((size_t)K_PRE * 16);
    float4*   Q    = (float4*)alloc((size_t)K_PRE * 16);
    float*    A    = (float*)alloc((size_t)K_PRE * 4);
    uint32_t* mask = (uint32_t*)alloc((size_t)ROWS_PAD * MW * 4);   // ~4.5 MB

    k_init<<<16, 256, 0, stream>>>(out, hist, meta);
    k_keys_hist<<<N_TOT / 256, 256, 0, stream>>>(scores, deltas, keys, hist);
    k_findbin<<<1, 256, 0, stream>>>(hist, meta);
    k_compact<<<N_TOT / 256, 256, 0, stream>>>(keys, meta, cand, meta + 1);
    k_rank_score<<<CAP / 256, 256, 0, stream>>>(cand, meta, top);
    k_props<<<(K_PRE + 255) / 256, 256, 0, stream>>>(top, deltas, P, yk);
    k_rank_y2<<<(K_PRE + 255) / 256, 256, 0, stream>>>(yk, P, OP, Q, A);
    k_mask<<<(K_PRE * MW + 255) / 256, 256, 0, stream>>>(Q, A, mask);
    k_scan<<<1, 256, 0, stream>>>(mask, OP, out);
}

// Round 3
// 553.138 us; speedup vs baseline: 1.6507x; 1.6507x over previous
//
#include <hip/hip_runtime.h>
#include <cstdint>
#include <cstddef>

#define N_TOT   147456      // 9*128*128
#define K_PRE   6000
#define K_POST  300
#define CAP     32768       // candidate cap (expected ~9.2K)
#define MW      188         // 6016 bits per mask row -> 188 u32 words
#define ROWS_PAD 6016
#define NCHUNK  94

__constant__ float c_sizes[9] = {4.f,8.f,12.f,16.f,24.f,32.f,48.f,64.f,96.f};

// Bit-exact replication of reference box math (anchor + delta, clip).
__device__ __forceinline__ void compute_box(int idx, const float* __restrict__ deltas,
                                            float& px1, float& py1, float& pw, float& ph) {
    int a   = idx >> 14;
    int rem = idx & 16383;
    int h   = rem >> 7;
    int w   = rem & 127;
    float s    = c_sizes[a];
    float half = s * 0.5f;
    const float4 d = *(const float4*)(deltas + (size_t)a * 65536 + (size_t)rem * 4);
    float b0 = (((float)h + 0.5f) - half) + d.x;
    float b1 = (((float)w + 0.5f) - half) + d.y;
    float b2 = s + d.z;
    float b3 = s + d.w;
    b0 = fmaxf(b0, 0.0f); b1 = fmaxf(b1, 0.0f);
    b2 = fmaxf(b2, 0.0f); b3 = fmaxf(b3, 0.0f);
    float x1 = b0, y1 = b1;
    float x2 = b0 + b2, y2 = b1 + b3;
    x1 = fminf(x1, 128.0f); y1 = fminf(y1, 128.0f);
    x2 = fminf(x2, 128.0f); y2 = fminf(y2, 128.0f);
    px1 = x1; py1 = y1; pw = x2 - x1; ph = y2 - y1;
}

__device__ __forceinline__ uint32_t waveReduceSum(uint32_t v) {
    #pragma unroll
    for (int o = 32; o > 0; o >>= 1) v += __shfl_xor(v, o, 64);
    return v;
}

__global__ void k_init(float* out, uint32_t* hist, uint32_t* meta) {
    int g = blockIdx.x * 256 + threadIdx.x;
    if (g < K_POST * 4) out[g] = 0.0f;
    if (g < 4096) hist[g] = 0u;
    if (g < 16) meta[g] = 0u;
}

__global__ void k_keys_hist(const float* __restrict__ scores, const float* __restrict__ deltas,
                            uint32_t* __restrict__ keys, uint32_t* __restrict__ hist) {
    __shared__ uint32_t lh[4096];
    for (int i = threadIdx.x; i < 4096; i += 256) lh[i] = 0u;
    __syncthreads();
    int idx = blockIdx.x * 256 + threadIdx.x;
    float px1, py1, pw, ph;
    compute_box(idx, deltas, px1, py1, pw, ph);
    bool keep = (pw >= 3.0f) && (ph >= 3.0f);
    float sc = scores[idx];
    uint32_t key = keep ? __float_as_uint(sc) : 0u;
    keys[idx] = key;
    atomicAdd(&lh[key >> 20], 1u);
    __syncthreads();
    for (int i = threadIdx.x; i < 4096; i += 256) {
        uint32_t v = lh[i];
        if (v) atomicAdd(&hist[i], v);
    }
}

__global__ void k_findbin(const uint32_t* __restrict__ hist, uint32_t* meta) {
    __shared__ uint32_t lh[4096];
    __shared__ uint32_t seg[256];
    for (int i = threadIdx.x; i < 4096; i += 256) lh[i] = hist[i];
    __syncthreads();
    uint32_t s = 0;
    for (int q = 0; q < 16; q++) s += lh[threadIdx.x * 16 + q];
    seg[threadIdx.x] = s;
    __syncthreads();
    if (threadIdx.x == 0) {
        uint32_t cum = 0;
        for (int t = 255; t >= 0; t--) {
            if (cum + seg[t] >= K_PRE) {
                uint32_t c2 = cum;
                for (int q = 15; q >= 0; q--) {
                    int bin = t * 16 + q;
                    c2 += lh[bin];
                    if (c2 >= K_PRE) { meta[0] = (uint32_t)bin; return; }
                }
            }
            cum += seg[t];
        }
        meta[0] = 0u;
    }
}

__global__ void k_compact(const uint32_t* __restrict__ keys, const uint32_t* __restrict__ meta,
                          uint64_t* __restrict__ cand, uint32_t* counter) {
    int idx = blockIdx.x * 256 + threadIdx.x;
    uint32_t bstar = meta[0];
    uint32_t key = keys[idx];
    if ((key >> 20) >= bstar) {
        uint32_t pos = atomicAdd(counter, 1u);
        if (pos < CAP) cand[pos] = ((uint64_t)key << 32) | (uint32_t)(~(uint32_t)idx);
    }
}

// wave handles 4 candidates: rank-by-count with coalesced global loads + shuffle reduce
__global__ void k_rank_score(const uint64_t* __restrict__ cand, const uint32_t* __restrict__ meta,
                             uint32_t* __restrict__ top) {
    uint32_t C = meta[1];
    if (C > CAP) C = CAP;
    int lane = threadIdx.x & 63;
    int wid  = (blockIdx.x * 256 + threadIdx.x) >> 6;
    const uint32_t totW = 1024 * 4;
    uint32_t nGroups = (C + 3) >> 2;
    for (uint32_t g = wid; g < nGroups; g += totW) {
        uint32_t b = g * 4;
        uint64_t m0 = (b + 0 < C) ? cand[b + 0] : ~0ull;
        uint64_t m1 = (b + 1 < C) ? cand[b + 1] : ~0ull;
        uint64_t m2 = (b + 2 < C) ? cand[b + 2] : ~0ull;
        uint64_t m3 = (b + 3 < C) ? cand[b + 3] : ~0ull;
        uint32_t c0 = 0, c1 = 0, c2 = 0, c3 = 0;
        for (uint32_t j = lane; j < C; j += 64) {
            uint64_t k = cand[j];
            c0 += (k > m0) ? 1u : 0u;
            c1 += (k > m1) ? 1u : 0u;
            c2 += (k > m2) ? 1u : 0u;
            c3 += (k > m3) ? 1u : 0u;
        }
        c0 = waveReduceSum(c0); c1 = waveReduceSum(c1);
        c2 = waveReduceSum(c2); c3 = waveReduceSum(c3);
        if (lane == 0) {
            if (b + 0 < C && c0 < K_PRE) top[c0] = ~((uint32_t)m0);
            if (b + 1 < C && c1 < K_PRE) top[c1] = ~((uint32_t)m1);
            if (b + 2 < C && c2 < K_PRE) top[c2] = ~((uint32_t)m2);
            if (b + 3 < C && c3 < K_PRE) top[c3] = ~((uint32_t)m3);
        }
    }
}

__global__ void k_props(const uint32_t* __restrict__ top, const float* __restrict__ deltas,
                        float4* __restrict__ P, uint64_t* __restrict__ ykey) {
    int r = blockIdx.x * 256 + threadIdx.x;
    if (r >= K_PRE) return;
    int idx = (int)top[r];
    float px1, py1, pw, ph;
    compute_box(idx, deltas, px1, py1, pw, ph);
    P[r] = make_float4(px1, py1, pw, ph);
    float y2 = py1 + ph;
    ykey[r] = ((uint64_t)__float_as_uint(y2) << 32) | (uint32_t)(~(uint32_t)r);
}

// wave handles 4 rows of the y2 stable-sort rank
__global__ void k_rank_y2(const uint64_t* __restrict__ ykey, const float4* __restrict__ P,
                          float4* __restrict__ OP, float4* __restrict__ Q, float* __restrict__ A) {
    int lane = threadIdx.x & 63;
    int wid  = (blockIdx.x * 256 + threadIdx.x) >> 6;   // 0..1499
    uint32_t b = wid * 4;
    uint64_t m0 = ykey[b + 0], m1 = ykey[b + 1], m2 = ykey[b + 2], m3 = ykey[b + 3];
    uint32_t c0 = 0, c1 = 0, c2 = 0, c3 = 0;
    for (uint32_t j = lane; j < K_PRE; j += 64) {
        uint64_t k = ykey[j];
        c0 += (k > m0) ? 1u : 0u;
        c1 += (k > m1) ? 1u : 0u;
        c2 += (k > m2) ? 1u : 0u;
        c3 += (k > m3) ? 1u : 0u;
    }
    c0 = waveReduceSum(c0); c1 = waveReduceSum(c1);
    c2 = waveReduceSum(c2); c3 = waveReduceSum(c3);
    if (lane == 0) {
        uint32_t rnk[4] = {c0, c1, c2, c3};
        #pragma unroll
        for (int q = 0; q < 4; q++) {
            float4 p = P[b + q];
            uint32_t cnt = rnk[q];
            OP[cnt] = p;
            float x1 = p.x, y1 = p.y;
            float x2 = x1 + p.z, y2 = y1 + p.w;
            float area = fmaxf((x2 - x1) * (y2 - y1), 1e-6f);
            Q[cnt] = make_float4(x1, y1, x2, y2);
            A[cnt] = area;
        }
    }
}

// suppression bitmask: bit j of row i = (ov[i][j] >= 0.7 && j != i). IEEE div kept.
__global__ void k_mask(const float4* __restrict__ Q, const float* __restrict__ A,
                       uint32_t* __restrict__ mask) {
    int g = blockIdx.x * 256 + threadIdx.x;
    if (g >= K_PRE * MW) return;
    int i  = g / MW;
    int wj = g - i * MW;
    float4 qi = Q[i];
    uint32_t bits = 0u;
    int jbase = wj * 32;
    #pragma unroll 4
    for (int b = 0; b < 32; b++) {
        int j = jbase + b;
        if (j < K_PRE && j != i) {
            float4 qj = Q[j];
            float iw = fminf(qi.z, qj.z) - fmaxf(qi.x, qj.x) + 1.0f;
            iw = fmaxf(iw, 0.0f);
            float ih = fminf(qi.w, qj.w) - fmaxf(qi.y, qj.y) + 1.0f;
            ih = fmaxf(ih, 0.0f);
            float ov = (iw * ih) / A[j];
            if (ov >= 0.7f) bits |= (1u << b);
        }
    }
    mask[(size_t)i * MW + wj] = bits;
}

// Serial ACTIVE scan only. Active(i) = no earlier active k with mask[k][i].
// rem[] accumulates active rows' bits into FUTURE column words only (words
// >= 2c+2); own-chunk kills handled in-register. Final validity (incl.
// backward kills) is computed later in parallel by k_valid.
__global__ void __launch_bounds__(256) k_scan_active(const uint32_t* __restrict__ mask,
        uint64_t* __restrict__ survArr, uint32_t* __restrict__ active_list,
        uint32_t* __restrict__ nactive) {
    __shared__ uint32_t rem[MW];
    __shared__ uint64_t survSh;
    for (int i = threadIdx.x; i < MW; i += 256) rem[i] = 0u;
    __syncthreads();
    int lane = threadIdx.x;
    uint32_t nact = 0;                       // maintained uniformly by wave 0
    for (int c = 0; c < NCHUNK; c++) {
        int base = c * 64;
        int rows = min(64, K_PRE - base);
        if (lane < 64) {
            const uint32_t* rp = mask + (size_t)(base + lane) * MW + 2 * c;
            uint2 mr = *(const uint2*)rp;     // lane's intra-chunk row (64 bits)
            uint32_t vlo = ~rem[2 * c];
            uint32_t vhi = ~rem[2 * c + 1];
            if (rows < 64) vhi &= (1u << (rows - 32)) - 1u;   // rows always >32 here (last=48)
            uint64_t surv = 0ull;
            #pragma unroll
            for (int g = 0; g < 64; g += 8) {
                uint32_t rl[8], rh[8];
                #pragma unroll
                for (int j = 0; j < 8; j++) {
                    rl[j] = (uint32_t)__builtin_amdgcn_readlane((int)mr.x, g + j);
                    rh[j] = (uint32_t)__builtin_amdgcn_readlane((int)mr.y, g + j);
                }
                #pragma unroll
                for (int j = 0; j < 8; j++) {
                    int kk = g + j;
                    uint32_t alive = (kk < 32) ? ((vlo >> kk) & 1u) : ((vhi >> (kk - 32)) & 1u);
                    if (alive) {
                        surv |= 1ull << kk;
                        vlo &= ~rl[j];
                        vhi &= ~rh[j];
                    }
                }
            }
            if (lane == 0) {
                survSh = surv;
                survArr[c] = surv;            // <-- R2 bug fix: was never stored
            }
            // compact active indices (surv is uniform across wave 0)
            if ((surv >> lane) & 1ull) {
                uint32_t pref = __popcll(surv & ((1ull << lane) - 1ull));
                active_list[nact + pref] = (uint32_t)(base + lane);
            }
            nact += (uint32_t)__popcll(surv);
        }
        __syncthreads();
        uint64_t surv = survSh;
        int wstart = 2 * c + 2;
        int nw = MW - wstart;
        if ((int)threadIdx.x < nw) {
            int w = wstart + threadIdx.x;
            uint32_t acc = rem[w];
            const uint32_t* mp = mask + (size_t)base * MW + w;
            uint64_t bset = surv;
            while (bset) {
                int k0 = __ffsll((unsigned long long)bset) - 1; bset &= bset - 1ull;
                if (bset) {
                    int k1 = __ffsll((unsigned long long)bset) - 1; bset &= bset - 1ull;
                    uint32_t t0 = mp[(size_t)k0 * MW];
                    uint32_t t1 = mp[(size_t)k1 * MW];
                    acc |= t0 | t1;
                } else {
                    acc |= mp[(size_t)k0 * MW];
                }
            }
            rem[w] = acc;
        }
        __syncthreads();
    }
    if (threadIdx.x == 0) nactive[0] = nact;
}

// Parallel final validity: valid[j] = active[j] && no ACTIVE i with mask[i][j].
// One block per 32-column word; OR over the compacted active-row list.
__global__ void k_valid(const uint32_t* __restrict__ mask, const uint64_t* __restrict__ survArr,
                        const uint32_t* __restrict__ active_list, const uint32_t* __restrict__ nactive,
                        uint32_t* __restrict__ validw) {
    __shared__ uint32_t red[256];
    int w = blockIdx.x;
    uint32_t A = nactive[0];
    uint32_t acc = 0u;
    for (uint32_t i = threadIdx.x; i < A; i += 256)
        acc |= mask[(size_t)active_list[i] * MW + w];
    red[threadIdx.x] = acc;
    __syncthreads();
    #pragma unroll
    for (int s = 128; s > 0; s >>= 1) {
        if (threadIdx.x < (unsigned)s) red[threadIdx.x] |= red[threadIdx.x + s];
        __syncthreads();
    }
    if (threadIdx.x == 0) {
        uint64_t sv = survArr[w >> 1];
        uint32_t aw = (uint32_t)(sv >> ((w & 1) * 32));
        validw[w] = aw & ~red[0];
    }
}

// first 300 valid rows (ascending position) -> out; tail stays zero (k_init)
__global__ void k_out(const uint32_t* __restrict__ validw, const float4* __restrict__ OP,
                      float* __restrict__ out) {
    __shared__ uint32_t vw[MW];
    __shared__ uint32_t pref[MW];
    if (threadIdx.x < MW) vw[threadIdx.x] = validw[threadIdx.x];
    __syncthreads();
    if (threadIdx.x == 0) {
        uint32_t run = 0;
        for (int w = 0; w < MW; w++) { pref[w] = run; run += (uint32_t)__popc(vw[w]); }
    }
    __syncthreads();
    if (threadIdx.x < MW) {
        uint32_t b = vw[threadIdx.x];
        uint32_t r = pref[threadIdx.x];
        int basebit = threadIdx.x * 32;
        while (b && r < K_POST) {
            int bit = __ffs(b) - 1;
            b &= b - 1u;
            float4 p = OP[basebit + bit];
            *(float4*)(out + (size_t)r * 4) = p;
            r++;
        }
    }
}

extern "C" void kernel_launch(void* const* d_in, const int* in_sizes, int n_in,
                              void* d_out, int out_size, void* d_ws, size_t ws_size,
                              hipStream_t stream) {
    (void)in_sizes; (void)n_in; (void)out_size; (void)ws_size;
    const float* scores = (const float*)d_in[0];
    const float* deltas = (const float*)d_in[1];
    float* out = (float*)d_out;

    char* ws = (char*)d_ws;
    size_t off = 0;
    auto alloc = [&](size_t bytes) -> void* {
        void* p = ws + off;
        off += (bytes + 255) & ~(size_t)255;
        return p;
    };
    uint32_t* keys  = (uint32_t*)alloc((size_t)N_TOT * 4);
    uint32_t* hist  = (uint32_t*)alloc(4096 * 4);
    uint32_t* meta  = (uint32_t*)alloc(64);
    uint64_t* cand  = (uint64_t*)alloc((size_t)CAP * 8);
    uint32_t* top   = (uint32_t*)alloc((size_t)K_PRE * 4);
    float4*   P     = (float4*)alloc((size_t)K_PRE * 16);
    uint64_t* yk    = (uint64_t*)alloc((size_t)K_PRE * 8);
    float4*   OP    = (float4*)alloc((size_t)K_PRE * 16);
    float4*   Q     = (float4*)alloc((size_t)K_PRE * 16);
    float*    A     = (float*)alloc((size_t)K_PRE * 4);
    uint32_t* mask  = (uint32_t*)alloc((size_t)ROWS_PAD * MW * 4);   // ~4.5 MB
    uint64_t* survA = (uint64_t*)alloc((size_t)NCHUNK * 8);
    uint32_t* alist = (uint32_t*)alloc((size_t)K_PRE * 4);
    uint32_t* nact  = (uint32_t*)alloc(64);
    uint32_t* valw  = (uint32_t*)alloc((size_t)MW * 4);

    k_init<<<16, 256, 0, stream>>>(out, hist, meta);
    k_keys_hist<<<N_TOT / 256, 256, 0, stream>>>(scores, deltas, keys, hist);
    k_findbin<<<1, 256, 0, stream>>>(hist, meta);
    k_compact<<<N_TOT / 256, 256, 0, stream>>>(keys, meta, cand, meta + 1);
    k_rank_score<<<1024, 256, 0, stream>>>(cand, meta, top);
    k_props<<<(K_PRE + 255) / 256, 256, 0, stream>>>(top, deltas, P, yk);
    k_rank_y2<<<375, 256, 0, stream>>>(yk, P, OP, Q, A);
    k_mask<<<(K_PRE * MW + 255) / 256, 256, 0, stream>>>(Q, A, mask);
    k_scan_active<<<1, 256, 0, stream>>>(mask, survA, alist, nact);
    k_valid<<<MW, 256, 0, stream>>>(mask, survA, alist, nact, valw);
    k_out<<<1, 256, 0, stream>>>(valw, OP, out);
}

// Round 4
// 390.261 us; speedup vs baseline: 2.3396x; 1.4174x over previous
//
#include <hip/hip_runtime.h>
#include <cstdint>
#include <cstddef>

#define N_TOT   147456      // 9*128*128
#define K_PRE   6000
#define K_POST  300
#define CAP     32768       // candidate cap (expected ~9.2K)
#define MW      188         // 6016 bits per mask row -> 188 u32 words
#define ROWS_PAD 6016
#define NCHUNK  94
#define CT      512         // k_mask columns per tile
#define ROWB    24          // ceil(6000/256) row blocks
#define COLB    12          // ceil(6000/512) col tiles

__constant__ float c_sizes[9] = {4.f,8.f,12.f,16.f,24.f,32.f,48.f,64.f,96.f};

// Bit-exact replication of reference box math (anchor + delta, clip).
__device__ __forceinline__ void compute_box(int idx, const float* __restrict__ deltas,
                                            float& px1, float& py1, float& pw, float& ph) {
    int a   = idx >> 14;
    int rem = idx & 16383;
    int h   = rem >> 7;
    int w   = rem & 127;
    float s    = c_sizes[a];
    float half = s * 0.5f;
    const float4 d = *(const float4*)(deltas + (size_t)a * 65536 + (size_t)rem * 4);
    float b0 = (((float)h + 0.5f) - half) + d.x;
    float b1 = (((float)w + 0.5f) - half) + d.y;
    float b2 = s + d.z;
    float b3 = s + d.w;
    b0 = fmaxf(b0, 0.0f); b1 = fmaxf(b1, 0.0f);
    b2 = fmaxf(b2, 0.0f); b3 = fmaxf(b3, 0.0f);
    float x1 = b0, y1 = b1;
    float x2 = b0 + b2, y2 = b1 + b3;
    x1 = fminf(x1, 128.0f); y1 = fminf(y1, 128.0f);
    x2 = fminf(x2, 128.0f); y2 = fminf(y2, 128.0f);
    px1 = x1; py1 = y1; pw = x2 - x1; ph = y2 - y1;
}

__device__ __forceinline__ uint32_t waveReduceSum(uint32_t v) {
    #pragma unroll
    for (int o = 32; o > 0; o >>= 1) v += __shfl_xor(v, o, 64);
    return v;
}

__global__ void k_init(float* out, uint32_t* hist, uint32_t* meta) {
    int g = blockIdx.x * 256 + threadIdx.x;
    if (g < K_POST * 4) out[g] = 0.0f;
    if (g < 4096) hist[g] = 0u;
    if (g < 16) meta[g] = 0u;
}

__global__ void k_keys_hist(const float* __restrict__ scores, const float* __restrict__ deltas,
                            uint32_t* __restrict__ keys, uint32_t* __restrict__ hist) {
    __shared__ uint32_t lh[4096];
    for (int i = threadIdx.x; i < 4096; i += 256) lh[i] = 0u;
    __syncthreads();
    int idx = blockIdx.x * 256 + threadIdx.x;
    float px1, py1, pw, ph;
    compute_box(idx, deltas, px1, py1, pw, ph);
    bool keep = (pw >= 3.0f) && (ph >= 3.0f);
    float sc = scores[idx];
    uint32_t key = keep ? __float_as_uint(sc) : 0u;
    keys[idx] = key;
    atomicAdd(&lh[key >> 20], 1u);
    __syncthreads();
    for (int i = threadIdx.x; i < 4096; i += 256) {
        uint32_t v = lh[i];
        if (v) atomicAdd(&hist[i], v);
    }
}

__global__ void k_findbin(const uint32_t* __restrict__ hist, uint32_t* meta) {
    __shared__ uint32_t lh[4096];
    __shared__ uint32_t seg[256];
    for (int i = threadIdx.x; i < 4096; i += 256) lh[i] = hist[i];
    __syncthreads();
    uint32_t s = 0;
    for (int q = 0; q < 16; q++) s += lh[threadIdx.x * 16 + q];
    seg[threadIdx.x] = s;
    __syncthreads();
    if (threadIdx.x == 0) {
        uint32_t cum = 0;
        for (int t = 255; t >= 0; t--) {
            if (cum + seg[t] >= K_PRE) {
                uint32_t c2 = cum;
                for (int q = 15; q >= 0; q--) {
                    int bin = t * 16 + q;
                    c2 += lh[bin];
                    if (c2 >= K_PRE) { meta[0] = (uint32_t)bin; return; }
                }
            }
            cum += seg[t];
        }
        meta[0] = 0u;
    }
}

__global__ void k_compact(const uint32_t* __restrict__ keys, const uint32_t* __restrict__ meta,
                          uint64_t* __restrict__ cand, uint32_t* counter) {
    int idx = blockIdx.x * 256 + threadIdx.x;
    uint32_t bstar = meta[0];
    uint32_t key = keys[idx];
    if ((key >> 20) >= bstar) {
        uint32_t pos = atomicAdd(counter, 1u);
        if (pos < CAP) cand[pos] = ((uint64_t)key << 32) | (uint32_t)(~(uint32_t)idx);
    }
}

// wave handles 4 candidates: rank-by-count with coalesced global loads + shuffle reduce
__global__ void k_rank_score(const uint64_t* __restrict__ cand, const uint32_t* __restrict__ meta,
                             uint32_t* __restrict__ top) {
    uint32_t C = meta[1];
    if (C > CAP) C = CAP;
    int lane = threadIdx.x & 63;
    int wid  = (blockIdx.x * 256 + threadIdx.x) >> 6;
    const uint32_t totW = 1024 * 4;
    uint32_t nGroups = (C + 3) >> 2;
    for (uint32_t g = wid; g < nGroups; g += totW) {
        uint32_t b = g * 4;
        uint64_t m0 = (b + 0 < C) ? cand[b + 0] : ~0ull;
        uint64_t m1 = (b + 1 < C) ? cand[b + 1] : ~0ull;
        uint64_t m2 = (b + 2 < C) ? cand[b + 2] : ~0ull;
        uint64_t m3 = (b + 3 < C) ? cand[b + 3] : ~0ull;
        uint32_t c0 = 0, c1 = 0, c2 = 0, c3 = 0;
        for (uint32_t j = lane; j < C; j += 64) {
            uint64_t k = cand[j];
            c0 += (k > m0) ? 1u : 0u;
            c1 += (k > m1) ? 1u : 0u;
            c2 += (k > m2) ? 1u : 0u;
            c3 += (k > m3) ? 1u : 0u;
        }
        c0 = waveReduceSum(c0); c1 = waveReduceSum(c1);
        c2 = waveReduceSum(c2); c3 = waveReduceSum(c3);
        if (lane == 0) {
            if (b + 0 < C && c0 < K_PRE) top[c0] = ~((uint32_t)m0);
            if (b + 1 < C && c1 < K_PRE) top[c1] = ~((uint32_t)m1);
            if (b + 2 < C && c2 < K_PRE) top[c2] = ~((uint32_t)m2);
            if (b + 3 < C && c3 < K_PRE) top[c3] = ~((uint32_t)m3);
        }
    }
}

__global__ void k_props(const uint32_t* __restrict__ top, const float* __restrict__ deltas,
                        float4* __restrict__ P, uint64_t* __restrict__ ykey) {
    int r = blockIdx.x * 256 + threadIdx.x;
    if (r >= K_PRE) return;
    int idx = (int)top[r];
    float px1, py1, pw, ph;
    compute_box(idx, deltas, px1, py1, pw, ph);
    P[r] = make_float4(px1, py1, pw, ph);
    float y2 = py1 + ph;
    ykey[r] = ((uint64_t)__float_as_uint(y2) << 32) | (uint32_t)(~(uint32_t)r);
}

// wave handles 4 rows of the y2 stable-sort rank; epilogue computes the exact
// fp32 decision boundary B[j]: pred( round(d/area) >= 0.7f ) <=> d >= B[j].
// M = 0.7f - 2^-25 (tie at midpoint rounds to even = predecessor => strict >).
// M*(double)area is exact (25x24 bits); B = smallest fp32 with (double)B > M*area.
__global__ void k_rank_y2(const uint64_t* __restrict__ ykey, const float4* __restrict__ P,
                          float4* __restrict__ OP, float4* __restrict__ Q, float* __restrict__ Bnd) {
    int lane = threadIdx.x & 63;
    int wid  = (blockIdx.x * 256 + threadIdx.x) >> 6;   // 0..1499
    uint32_t b = wid * 4;
    uint64_t m0 = ykey[b + 0], m1 = ykey[b + 1], m2 = ykey[b + 2], m3 = ykey[b + 3];
    uint32_t c0 = 0, c1 = 0, c2 = 0, c3 = 0;
    for (uint32_t j = lane; j < K_PRE; j += 64) {
        uint64_t k = ykey[j];
        c0 += (k > m0) ? 1u : 0u;
        c1 += (k > m1) ? 1u : 0u;
        c2 += (k > m2) ? 1u : 0u;
        c3 += (k > m3) ? 1u : 0u;
    }
    c0 = waveReduceSum(c0); c1 = waveReduceSum(c1);
    c2 = waveReduceSum(c2); c3 = waveReduceSum(c3);
    if (lane == 0) {
        const double Mc = (double)0.7f - 0x1.0p-25;
        uint32_t rnk[4] = {c0, c1, c2, c3};
        #pragma unroll
        for (int q = 0; q < 4; q++) {
            float4 p = P[b + q];
            uint32_t cnt = rnk[q];
            OP[cnt] = p;
            float x1 = p.x, y1 = p.y;
            float x2 = x1 + p.z, y2 = y1 + p.w;
            float area = fmaxf((x2 - x1) * (y2 - y1), 1e-6f);
            Q[cnt] = make_float4(x1, y1, x2, y2);
            double c = Mc * (double)area;       // exact
            float Bf = (float)c;
            if (!((double)Bf > c)) Bf = __int_as_float(__float_as_int(Bf) + 1); // next up (Bf>0)
            Bnd[cnt] = Bf;
        }
    }
}

// suppression bitmask, tiled: lanes = rows (row box in regs), columns staged in
// LDS and read as wave-broadcast (conflict-free). No division: d >= Bnd[j].
__global__ void __launch_bounds__(256) k_mask(const float4* __restrict__ Q,
                                              const float* __restrict__ Bnd,
                                              uint32_t* __restrict__ mask) {
    __shared__ float4 qs[CT];
    __shared__ float  bs[CT];
    int i  = blockIdx.x * 256 + threadIdx.x;     // row
    int c0 = blockIdx.y * CT;                    // first column of tile
    int ncols = min(CT, K_PRE - c0);
    for (int j = threadIdx.x; j < ncols; j += 256) {
        qs[j] = Q[c0 + j];
        bs[j] = Bnd[c0 + j];
    }
    __syncthreads();
    bool rowok = (i < K_PRE);
    float4 qi = rowok ? Q[i] : make_float4(0.f, 0.f, 0.f, 0.f);
    int nw = (ncols + 31) >> 5;
    for (int w = 0; w < nw; w++) {
        uint32_t bits = 0u;
        int jb = w * 32;
        int jn = min(32, ncols - jb);
        #pragma unroll 8
        for (int b = 0; b < jn; b++) {
            int j = jb + b;
            float4 qj = qs[j];
            float iw = fminf(qi.z, qj.z) - fmaxf(qi.x, qj.x) + 1.0f;
            iw = fmaxf(iw, 0.0f);
            float ih = fminf(qi.w, qj.w) - fmaxf(qi.y, qj.y) + 1.0f;
            ih = fmaxf(ih, 0.0f);
            float d = iw * ih;
            bits |= (d >= bs[j]) ? (1u << b) : 0u;
        }
        if (rowok) {
            int gj = c0 + jb;
            uint32_t selfo = (uint32_t)(i - gj);
            if (selfo < 32u) bits &= ~(1u << selfo);     // j == i excluded
            mask[(size_t)i * MW + (gj >> 5)] = bits;
        }
    }
}

// Serial ACTIVE scan. Active(i) = no earlier active k with mask[k][i].
// Wave 0: decide (readlane-broadcast chain), compact survivors, prefetch next
// chunk's intra-block rows. Threads 64..255: OR surviving rows into FUTURE
// column words of rem (one word/thread, 8-wide independent load batches).
__global__ void __launch_bounds__(256) k_scan_active(const uint32_t* __restrict__ mask,
        uint64_t* __restrict__ survArr, uint32_t* __restrict__ active_list,
        uint32_t* __restrict__ nactive) {
    __shared__ uint32_t rem[MW];
    __shared__ uint32_t sidx[64];
    __shared__ uint32_t snum;
    for (int i = threadIdx.x; i < MW; i += 256) rem[i] = 0u;
    __syncthreads();
    int tid = threadIdx.x;
    uint32_t nact = 0;                           // wave-0-uniform
    uint2 mr = make_uint2(0u, 0u);
    if (tid < 64) mr = *(const uint2*)(mask + (size_t)tid * MW);   // chunk 0 prefetch
    for (int c = 0; c < NCHUNK; c++) {
        int base = c * 64;
        int rows = min(64, K_PRE - base);
        if (tid < 64) {
            uint32_t vlo = ~rem[2 * c];
            uint32_t vhi = ~rem[2 * c + 1];
            if (rows < 64) vhi &= (1u << (rows - 32)) - 1u;
            uint64_t surv = 0ull;
            #pragma unroll
            for (int g = 0; g < 64; g += 8) {
                uint32_t rl[8], rh[8];
                #pragma unroll
                for (int j = 0; j < 8; j++) {
                    rl[j] = (uint32_t)__builtin_amdgcn_readlane((int)mr.x, g + j);
                    rh[j] = (uint32_t)__builtin_amdgcn_readlane((int)mr.y, g + j);
                }
                #pragma unroll
                for (int j = 0; j < 8; j++) {
                    int kk = g + j;
                    uint32_t alive = (kk < 32) ? ((vlo >> kk) & 1u) : ((vhi >> (kk - 32)) & 1u);
                    if (alive) {
                        surv |= 1ull << kk;
                        vlo &= ~rl[j];
                        vhi &= ~rh[j];
                    }
                }
            }
            if (tid == 0) {
                survArr[c] = surv;
                snum = (uint32_t)__popcll(surv);
            }
            if ((surv >> tid) & 1ull) {
                uint32_t pref = __popcll(surv & ((1ull << tid) - 1ull));
                uint32_t gi = (uint32_t)(base + tid);
                sidx[pref] = gi;
                active_list[nact + pref] = gi;
            }
            nact += (uint32_t)__popcll(surv);
            if (c + 1 < NCHUNK)                  // prefetch next chunk (overlaps OR phase)
                mr = *(const uint2*)(mask + (size_t)(base + 64 + tid) * MW + 2 * (c + 1));
        }
        __syncthreads();
        int w = 2 * c + 2 + (tid - 64);
        if (tid >= 64 && w < MW) {
            uint32_t ns = snum;
            uint32_t acc = rem[w];
            uint32_t t = 0;
            for (; t + 8 <= ns; t += 8) {
                uint32_t r0 = mask[(size_t)sidx[t + 0] * MW + w];
                uint32_t r1 = mask[(size_t)sidx[t + 1] * MW + w];
                uint32_t r2 = mask[(size_t)sidx[t + 2] * MW + w];
                uint32_t r3 = mask[(size_t)sidx[t + 3] * MW + w];
                uint32_t r4 = mask[(size_t)sidx[t + 4] * MW + w];
                uint32_t r5 = mask[(size_t)sidx[t + 5] * MW + w];
                uint32_t r6 = mask[(size_t)sidx[t + 6] * MW + w];
                uint32_t r7 = mask[(size_t)sidx[t + 7] * MW + w];
                acc |= (r0 | r1) | (r2 | r3) | ((r4 | r5) | (r6 | r7));
            }
            for (; t < ns; t++) acc |= mask[(size_t)sidx[t] * MW + w];
            rem[w] = acc;
        }
        __syncthreads();
    }
    if (tid == 0) nactive[0] = nact;
}

// Parallel final validity: valid[j] = active[j] && no ACTIVE i with mask[i][j].
__global__ void k_valid(const uint32_t* __restrict__ mask, const uint64_t* __restrict__ survArr,
                        const uint32_t* __restrict__ active_list, const uint32_t* __restrict__ nactive,
                        uint32_t* __restrict__ validw) {
    __shared__ uint32_t red[256];
    int w = blockIdx.x;
    uint32_t A = nactive[0];
    uint32_t acc = 0u;
    for (uint32_t i = threadIdx.x; i < A; i += 256)
        acc |= mask[(size_t)active_list[i] * MW + w];
    red[threadIdx.x] = acc;
    __syncthreads();
    #pragma unroll
    for (int s = 128; s > 0; s >>= 1) {
        if (threadIdx.x < (unsigned)s) red[threadIdx.x] |= red[threadIdx.x + s];
        __syncthreads();
    }
    if (threadIdx.x == 0) {
        uint64_t sv = survArr[w >> 1];
        uint32_t aw = (uint32_t)(sv >> ((w & 1) * 32));
        validw[w] = aw & ~red[0];
    }
}

// first 300 valid rows (ascending position) -> out; tail stays zero (k_init)
__global__ void k_out(const uint32_t* __restrict__ validw, const float4* __restrict__ OP,
                      float* __restrict__ out) {
    __shared__ uint32_t vw[MW];
    __shared__ uint32_t pref[MW];
    if (threadIdx.x < MW) vw[threadIdx.x] = validw[threadIdx.x];
    __syncthreads();
    if (threadIdx.x == 0) {
        uint32_t run = 0;
        for (int w = 0; w < MW; w++) { pref[w] = run; run += (uint32_t)__popc(vw[w]); }
    }
    __syncthreads();
    if (threadIdx.x < MW) {
        uint32_t b = vw[threadIdx.x];
        uint32_t r = pref[threadIdx.x];
        int basebit = threadIdx.x * 32;
        while (b && r < K_POST) {
            int bit = __ffs(b) - 1;
            b &= b - 1u;
            float4 p = OP[basebit + bit];
            *(float4*)(out + (size_t)r * 4) = p;
            r++;
        }
    }
}

extern "C" void kernel_launch(void* const* d_in, const int* in_sizes, int n_in,
                              void* d_out, int out_size, void* d_ws, size_t ws_size,
                              hipStream_t stream) {
    (void)in_sizes; (void)n_in; (void)out_size; (void)ws_size;
    const float* scores = (const float*)d_in[0];
    const float* deltas = (const float*)d_in[1];
    float* out = (float*)d_out;

    char* ws = (char*)d_ws;
    size_t off = 0;
    auto alloc = [&](size_t bytes) -> void* {
        void* p = ws + off;
        off += (bytes + 255) & ~(size_t)255;
        return p;
    };
    uint32_t* keys  = (uint32_t*)alloc((size_t)N_TOT * 4);
    uint32_t* hist  = (uint32_t*)alloc(4096 * 4);
    uint32_t* meta  = (uint32_t*)alloc(64);
    uint64_t* cand  = (uint64_t*)alloc((size_t)CAP * 8);
    uint32_t* top   = (uint32_t*)alloc((size_t)K_PRE * 4);
    float4*   P     = (float4*)alloc((size_t)K_PRE * 16);
    uint64_t* yk    = (uint64_t*)alloc((size_t)K_PRE * 8);
    float4*   OP    = (float4*)alloc((size_t)K_PRE * 16);
    float4*   Q     = (float4*)alloc((size_t)K_PRE * 16);
    float*    Bnd   = (float*)alloc((size_t)K_PRE * 4);
    uint32_t* mask  = (uint32_t*)alloc((size_t)ROWS_PAD * MW * 4);   // ~4.5 MB
    uint64_t* survA = (uint64_t*)alloc((size_t)NCHUNK * 8);
    uint32_t* alist = (uint32_t*)alloc((size_t)K_PRE * 4);
    uint32_t* nact  = (uint32_t*)alloc(64);
    uint32_t* valw  = (uint32_t*)alloc((size_t)MW * 4);

    k_init<<<16, 256, 0, stream>>>(out, hist, meta);
    k_keys_hist<<<N_TOT / 256, 256, 0, stream>>>(scores, deltas, keys, hist);
    k_findbin<<<1, 256, 0, stream>>>(hist, meta);
    k_compact<<<N_TOT / 256, 256, 0, stream>>>(keys, meta, cand, meta + 1);
    k_rank_score<<<1024, 256, 0, stream>>>(cand, meta, top);
    k_props<<<(K_PRE + 255) / 256, 256, 0, stream>>>(top, deltas, P, yk);
    k_rank_y2<<<375, 256, 0, stream>>>(yk, P, OP, Q, Bnd);
    k_mask<<<dim3(ROWB, COLB), 256, 0, stream>>>(Q, Bnd, mask);
    k_scan_active<<<1, 256, 0, stream>>>(mask, survA, alist, nact);
    k_valid<<<MW, 256, 0, stream>>>(mask, survA, alist, nact, valw);
    k_out<<<1, 256, 0, stream>>>(valw, OP, out);
}